// Round 9
// baseline (123.132 us; speedup 1.0000x reference)
//
#include <hip/hip_runtime.h>

// RBF-MMD discriminator: B=512 rows, T=128 slabs, C=16, fp32.
// out = E_xx - 2*E_xy over per-slab RBF grams (slab weight 1 for t in {0,127},
// else 2; 254 weighted slab instances).
//
// R9 structure: R8's differential matched the issue model (-3 us predicted and
// measured) but a structure-invariant ~17 us remained -> stall cycles: each
// block was a 2-phase convoy (scattered staging loads ~500-900 cyc, barrier,
// ~700 cyc compute), phases aligned across lockstep block generations.
// Fix: 4 t-slabs per block, double-buffered LDS, register prefetch of t+1
// issued before t's compute; one barrier per t. Grid 832 blocks ~3.25/CU ->
// whole grid co-resident; staging latency exposed once at prologue only.
//
// Numerics = R8 (passed, absmax 0.0): pure-bf16 dot via 16x16x32 MFMA,
// column norm folded into free K-slots (k16,k17 = -g_col hi/lo vs A=1.0),
// acc = log2e*(dot - |col|^2/2); per-entry work = exp2 + add.
// Row-scale 2^-g_row (+ slab/symmetry weight) in per-t epilogue.
// Kxx symmetry: strip-pairs q>=a only, q>a weighted 2x (exact).

#define LOG2E 1.4426950408889634f
#define SCALE 1.2011224087864498f   // sqrt(LOG2E)
#define NT 4                        // t-slabs per block

typedef __attribute__((ext_vector_type(8))) __bf16 bf16x8;
typedef __attribute__((ext_vector_type(4))) float floatx4;

union FragU { uint4 q; unsigned int u[4]; bf16x8 v; };

// 16B-aligned group-padded LDS row offset (dwords): 8 dw/row + 4 dw pad per 4 rows.
static __device__ __forceinline__ int off(int n) { return (n << 3) + ((n >> 2) << 2); }

static __device__ __forceinline__ unsigned short bfbits(__bf16 h) {
    union { __bf16 h; unsigned short s; } u; u.h = h; return u.s;
}
static __device__ __forceinline__ unsigned int packhh(__bf16 a, __bf16 b) {
    return (unsigned int)bfbits(a) | ((unsigned int)bfbits(b) << 16);
}

#define NSLOT 26
#define ONEONE 0x3F803F80u   // packed bf16 {1.0, 1.0}

// grid (26,32): blockIdx.x = pair slot, blockIdx.y = t-group (4 t's).
// slot<16: xy block, a=slot>>2 (A strip of X), q=slot&3 (col strip of Y).
// slot>=16: xx block over triangular (a,q), q>=a, weight 2 if q>a.
// 4 waves; wave w owns A rows a*128 + w*32 (two 16-row tiles).
__global__ __launch_bounds__(256, 4) void mmd_kernel(const float* __restrict__ x,
                                                     const float* __restrict__ y,
                                                     float* __restrict__ part) {
    __shared__ unsigned int AH[2][1152], BH[2][1152];
    __shared__ unsigned int BG[2][512];   // per B-row: {pack(-ghi,-glo),0,0,0}
    __shared__ float srg[2][128];         // g per A-row
    __shared__ unsigned int zero4[4];
    __shared__ float red[4];

    const int slot = blockIdx.x;
    const int t0   = blockIdx.y * NT;
    const int tid  = threadIdx.x;
    const int w    = tid >> 6;
    const int lane = tid & 63;
    const int quad = lane >> 4;
    const int l15  = lane & 15;
    const int qh   = quad & 1;

    int sa, sq, isxx;
    if (slot < 16) { isxx = 0; sa = slot >> 2; sq = slot & 3; }
    else {
        isxx = 1;
        const int s = slot - 16;
        if      (s < 4) { sa = 0; sq = s; }
        else if (s < 7) { sa = 1; sq = s - 3; }
        else if (s < 9) { sa = 2; sq = s - 5; }
        else            { sa = 3; sq = 3; }
    }

    if (tid == 0) { zero4[0] = 0u; zero4[1] = 0u; zero4[2] = 0u; zero4[3] = 0u; }

    // staging identity for this thread: half 0 = A-rows (X), 1 = B-rows (X or Y)
    const int half = tid >> 7;
    const int r    = tid & 127;
    const float4* __restrict__ src4 =
        (half && !isxx) ? (const float4*)y : (const float4*)x;
    const size_t rowbase = (size_t)((half ? sq : sa) * 128 + r) * 512;

    // conversion + LDS write of one staged row into buffer `buf`
    auto stage = [&](int buf, float4 f0, float4 f1, float4 f2, float4 f3) {
        const float fs[16] = { f0.x, f0.y, f0.z, f0.w, f1.x, f1.y, f1.z, f1.w,
                               f2.x, f2.y, f2.z, f2.w, f3.x, f3.y, f3.z, f3.w };
        float g = 0.f;
        unsigned int hw[8];
#pragma unroll
        for (int p = 0; p < 8; ++p) {
            const float v0 = fs[2 * p], v1 = fs[2 * p + 1];
            g += v0 * v0 + v1 * v1;
            hw[p] = packhh((__bf16)(v0 * SCALE), (__bf16)(v1 * SCALE));
        }
        const float gp = 0.5f * LOG2E * g;
        unsigned int* __restrict__ H = half ? BH[buf] : AH[buf];
        const int o = off(r);
        *(uint4*)&H[o]     = make_uint4(hw[0], hw[1], hw[2], hw[3]);
        *(uint4*)&H[o + 4] = make_uint4(hw[4], hw[5], hw[6], hw[7]);
        if (half) {
            const __bf16 nh = (__bf16)(-gp);
            const __bf16 nl = (__bf16)(-(gp + (float)nh));
            *(uint4*)&BG[buf][r * 4] = make_uint4(packhh(nh, nl), 0u, 0u, 0u);
        } else {
            srg[buf][r] = gp;
        }
    };

    // ---- prologue: stage t0 into buffer 0 ----
    {
        const size_t gb = rowbase + t0 * 4;
        stage(0, src4[gb], src4[gb + 1], src4[gb + 2], src4[gb + 3]);
    }
    __syncthreads();

    float tot = 0.f;

#pragma unroll
    for (int tt = 0; tt < NT; ++tt) {
        const int buf = tt & 1;
        const int t   = t0 + tt;

        // prefetch next slab's row (issues early; no deps on current compute)
        float4 p0, p1, p2, p3;
        if (tt < NT - 1) {
            const size_t gb = rowbase + (t + 1) * 4;
            p0 = src4[gb]; p1 = src4[gb + 1]; p2 = src4[gb + 2]; p3 = src4[gb + 3];
        }

        // ---- A fragments for this buffer ----
        bf16x8 a1f[2];
#pragma unroll
        for (int rt = 0; rt < 2; ++rt) {
            FragU u;
            if (quad < 2) {
                const int row = w * 32 + rt * 16 + l15;
                u.q = *(const uint4*)&AH[buf][off(row) + qh * 4];
            } else {
                u.q = make_uint4((quad == 2) ? ONEONE : 0u, 0u, 0u, 0u);
            }
            a1f[rt] = u.v;
        }

        // per-lane B-fragment pointer + per-jt stride (dwords)
        const unsigned int* bptr;
        int bstride;
        if (quad < 2)       { bptr = &BH[buf][off(l15) + qh * 4]; bstride = 144; }
        else if (quad == 2) { bptr = &BG[buf][l15 * 4];           bstride = 64;  }
        else                { bptr = &zero4[0];                   bstride = 0;   }

        float sum[2][4] = {{0.f, 0.f, 0.f, 0.f}, {0.f, 0.f, 0.f, 0.f}};

        // ---- pipelined main loop: MFMA tile jt, exp tile jt-1 ----
        floatx4 accP[2], accC[2];
        {
            FragU b; b.q = *(const uint4*)bptr; bptr += bstride;
            floatx4 zc = {0.f, 0.f, 0.f, 0.f};
            accP[0] = __builtin_amdgcn_mfma_f32_16x16x32_bf16(a1f[0], b.v, zc, 0, 0, 0);
            accP[1] = __builtin_amdgcn_mfma_f32_16x16x32_bf16(a1f[1], b.v, zc, 0, 0, 0);
        }
#pragma unroll
        for (int jt = 1; jt < 8; ++jt) {
            FragU b; b.q = *(const uint4*)bptr; bptr += bstride;
            floatx4 zc = {0.f, 0.f, 0.f, 0.f};
            accC[0] = __builtin_amdgcn_mfma_f32_16x16x32_bf16(a1f[0], b.v, zc, 0, 0, 0);
            accC[1] = __builtin_amdgcn_mfma_f32_16x16x32_bf16(a1f[1], b.v, zc, 0, 0, 0);
#pragma unroll
            for (int rt = 0; rt < 2; ++rt)
#pragma unroll
                for (int rr = 0; rr < 4; ++rr)
                    sum[rt][rr] += __builtin_amdgcn_exp2f(accP[rt][rr]);
            accP[0] = accC[0];
            accP[1] = accC[1];
        }
#pragma unroll
        for (int rt = 0; rt < 2; ++rt)
#pragma unroll
            for (int rr = 0; rr < 4; ++rr)
                sum[rt][rr] += __builtin_amdgcn_exp2f(accP[rt][rr]);

        // ---- per-t epilogue: weighted row-scale into running total ----
        float wt = (t == 0 || t == 127) ? 1.f : 2.f;
        if (isxx && sq > sa) wt *= 2.f;
#pragma unroll
        for (int rt = 0; rt < 2; ++rt)
#pragma unroll
            for (int rr = 0; rr < 4; ++rr) {
                const float rs =
                    wt * __builtin_amdgcn_exp2f(-srg[buf][w * 32 + rt * 16 + quad * 4 + rr]);
                tot = fmaf(sum[rt][rr], rs, tot);
            }

        // ---- stage prefetched slab into the other buffer ----
        if (tt < NT - 1) {
            stage(buf ^ 1, p0, p1, p2, p3);
            __syncthreads();
        }
    }

    // ---- block reduction, one store per block ----
    for (int o = 32; o > 0; o >>= 1) tot += __shfl_down(tot, o, 64);
    if (lane == 0) red[w] = tot;
    __syncthreads();
    if (tid == 0)
        part[slot * 32 + blockIdx.y] = red[0] + red[1] + red[2] + red[3];
}

__global__ __launch_bounds__(256) void finalize_kernel(const float* __restrict__ part,
                                                       float* __restrict__ out) {
    const int tid = threadIdx.x;
    // part[slot*32+ty]: slots 0..15 xy -> idx [0,512); slots 16..25 xx -> [512,832)
    double vxy = (double)part[tid] + (double)part[256 + tid];
    double vxx = (double)part[512 + tid];
    if (tid < 64) vxx += (double)part[768 + tid];
    for (int o = 32; o > 0; o >>= 1) {
        vxx += __shfl_down(vxx, o, 64);
        vxy += __shfl_down(vxy, o, 64);
    }
    __shared__ double red[8];
    const int wid = tid >> 6;
    if ((tid & 63) == 0) { red[wid] = vxx; red[4 + wid] = vxy; }
    __syncthreads();
    if (tid == 0) {
        double sxx = red[0] + red[1] + red[2] + red[3];
        double sxy = red[4] + red[5] + red[6] + red[7];
        // diagonal entries (~1.0 each) included in sxx: subtract 254*512
        double e1 = (sxx - 254.0 * 512.0) / (254.0 * 512.0 * 511.0);
        double e2 = sxy / (254.0 * 512.0 * 512.0);
        out[0] = (float)(e1 - 2.0 * e2);
    }
}

extern "C" void kernel_launch(void* const* d_in, const int* in_sizes, int n_in,
                              void* d_out, int out_size, void* d_ws, size_t ws_size,
                              hipStream_t stream) {
    (void)in_sizes; (void)n_in; (void)out_size; (void)ws_size;
    const float* x = (const float*)d_in[0];
    const float* y = (const float*)d_in[1];
    float* out  = (float*)d_out;
    float* part = (float*)d_ws;   // 832 floats: [0,512) xy, [512,832) xx

    mmd_kernel<<<dim3(NSLOT, 32), dim3(256), 0, stream>>>(x, y, part);
    finalize_kernel<<<dim3(1), dim3(256), 0, stream>>>(part, out);
}

// Round 10
// 74.546 us; speedup vs baseline: 1.6518x; 1.6518x over previous
//
#include <hip/hip_runtime.h>

// RBF-MMD discriminator: B=512 rows, T=128 slabs, C=16, fp32.
// out = E_xx - 2*E_xy over per-slab RBF grams (slab weight 1 for t in {0,127},
// else 2; 254 weighted slab instances).
//
// R10 structure: R9's profile showed 134MB WRITE / 86MB FETCH — the staging
// lambda (by-ref captures + local arrays + prefetch regs held across the MFMA
// loop) made the compiler spill to scratch; ~220MB of private-memory round
// trips WAS the 68us. Fix: no lambda, no local arrays — staging hand-unrolled
// on float4 components into named scalars. Architecture unchanged from R9:
// 4 t-slabs per block, double-buffered LDS, register prefetch of t+1 before
// t's compute, one barrier per slab; grid 832 blocks (~3.25/CU) co-resident
// so staging latency is exposed only at the prologue.
//
// Numerics = R8 (passed, absmax 0.0): pure-bf16 dot via 16x16x32 MFMA,
// column norm folded into free K-slots (k16,k17 = -g_col hi/lo vs A=1.0),
// acc = log2e*(dot - |col|^2/2); per-entry work = exp2 + add.
// Row-scale 2^-g_row (+ slab/symmetry weight) in per-t epilogue.
// Kxx symmetry: strip-pairs q>=a only, q>a weighted 2x (exact).

#define LOG2E 1.4426950408889634f
#define SCALE 1.2011224087864498f   // sqrt(LOG2E)
#define NT 4                        // t-slabs per block
#define NSLOT 26
#define ONEONE 0x3F803F80u          // packed bf16 {1.0, 1.0}

typedef __attribute__((ext_vector_type(8))) __bf16 bf16x8;
typedef __attribute__((ext_vector_type(4))) float floatx4;

union FragU { uint4 q; unsigned int u[4]; bf16x8 v; };

// 16B-aligned group-padded LDS row offset (dwords): 8 dw/row + 4 dw pad per 4 rows.
static __device__ __forceinline__ int off(int n) { return (n << 3) + ((n >> 2) << 2); }

static __device__ __forceinline__ unsigned short bfbits(__bf16 h) {
    union { __bf16 h; unsigned short s; } u; u.h = h; return u.s;
}
static __device__ __forceinline__ unsigned int packhh(__bf16 a, __bf16 b) {
    return (unsigned int)bfbits(a) | ((unsigned int)bfbits(b) << 16);
}
static __device__ __forceinline__ unsigned int packff(float a, float b) {
    return packhh((__bf16)(a * SCALE), (__bf16)(b * SCALE));
}

// staging: convert one row (4 float4s) to bf16 + norm, write LDS. No arrays,
// no lambda — all named scalars, by-value args (spill-proof).
static __device__ __forceinline__ void stage_row(int half, int r,
                                                 float4 f0, float4 f1,
                                                 float4 f2, float4 f3,
                                                 unsigned int* __restrict__ AHb,
                                                 unsigned int* __restrict__ BHb,
                                                 unsigned int* __restrict__ BGb,
                                                 float* __restrict__ srgb) {
    const float g =
        (f0.x * f0.x + f0.y * f0.y + f0.z * f0.z + f0.w * f0.w) +
        (f1.x * f1.x + f1.y * f1.y + f1.z * f1.z + f1.w * f1.w) +
        (f2.x * f2.x + f2.y * f2.y + f2.z * f2.z + f2.w * f2.w) +
        (f3.x * f3.x + f3.y * f3.y + f3.z * f3.z + f3.w * f3.w);
    const unsigned int hw0 = packff(f0.x, f0.y);
    const unsigned int hw1 = packff(f0.z, f0.w);
    const unsigned int hw2 = packff(f1.x, f1.y);
    const unsigned int hw3 = packff(f1.z, f1.w);
    const unsigned int hw4 = packff(f2.x, f2.y);
    const unsigned int hw5 = packff(f2.z, f2.w);
    const unsigned int hw6 = packff(f3.x, f3.y);
    const unsigned int hw7 = packff(f3.z, f3.w);
    unsigned int* __restrict__ H = half ? BHb : AHb;
    const int o = off(r);
    *(uint4*)&H[o]     = make_uint4(hw0, hw1, hw2, hw3);
    *(uint4*)&H[o + 4] = make_uint4(hw4, hw5, hw6, hw7);
    const float gp = 0.5f * LOG2E * g;
    if (half) {
        const __bf16 nh = (__bf16)(-gp);
        const __bf16 nl = (__bf16)(-(gp + (float)nh));
        *(uint4*)&BGb[r * 4] = make_uint4(packhh(nh, nl), 0u, 0u, 0u);
    } else {
        srgb[r] = gp;
    }
}

// grid (26,32): blockIdx.x = pair slot, blockIdx.y = t-group (4 t's).
// slot<16: xy block, a=slot>>2 (A strip of X), q=slot&3 (col strip of Y).
// slot>=16: xx block over triangular (a,q), q>=a, weight 2 if q>a.
// 4 waves; wave w owns A rows a*128 + w*32 (two 16-row tiles).
__global__ __launch_bounds__(256, 4) void mmd_kernel(const float* __restrict__ x,
                                                     const float* __restrict__ y,
                                                     float* __restrict__ part) {
    __shared__ unsigned int AH[2][1152], BH[2][1152];
    __shared__ unsigned int BG[2][512];   // per B-row: {pack(-ghi,-glo),0,0,0}
    __shared__ float srg[2][128];         // g per A-row
    __shared__ unsigned int zero4[4];
    __shared__ float red[4];

    const int slot = blockIdx.x;
    const int t0   = blockIdx.y * NT;
    const int tid  = threadIdx.x;
    const int w    = tid >> 6;
    const int lane = tid & 63;
    const int quad = lane >> 4;
    const int l15  = lane & 15;
    const int qh   = quad & 1;

    int sa, sq, isxx;
    if (slot < 16) { isxx = 0; sa = slot >> 2; sq = slot & 3; }
    else {
        isxx = 1;
        const int s = slot - 16;
        if      (s < 4) { sa = 0; sq = s; }
        else if (s < 7) { sa = 1; sq = s - 3; }
        else if (s < 9) { sa = 2; sq = s - 5; }
        else            { sa = 3; sq = 3; }
    }

    if (tid == 0) { zero4[0] = 0u; zero4[1] = 0u; zero4[2] = 0u; zero4[3] = 0u; }

    // staging identity: threads 0..127 = A-rows (X), 128..255 = B-rows (X or Y)
    const int half = tid >> 7;
    const int r    = tid & 127;
    const float4* __restrict__ src4 =
        (half && !isxx) ? (const float4*)y : (const float4*)x;
    const size_t rowbase = (size_t)((half ? sq : sa) * 128 + r) * 512;

    // ---- prologue: stage t0 into buffer 0 ----
    {
        const size_t gb = rowbase + (size_t)t0 * 4;
        stage_row(half, r, src4[gb], src4[gb + 1], src4[gb + 2], src4[gb + 3],
                  AH[0], BH[0], BG[0], srg[0]);
    }
    __syncthreads();

    float tot = 0.f;

#pragma unroll
    for (int tt = 0; tt < NT; ++tt) {
        const int buf = tt & 1;
        const int t   = t0 + tt;

        // prefetch next slab's row (no deps on current compute; issues early)
        float4 p0, p1, p2, p3;
        if (tt < NT - 1) {
            const size_t gb = rowbase + (size_t)(t + 1) * 4;
            p0 = src4[gb]; p1 = src4[gb + 1]; p2 = src4[gb + 2]; p3 = src4[gb + 3];
        }

        // ---- A fragments for this buffer ----
        bf16x8 a1f[2];
#pragma unroll
        for (int rt = 0; rt < 2; ++rt) {
            FragU u;
            if (quad < 2) {
                const int row = w * 32 + rt * 16 + l15;
                u.q = *(const uint4*)&AH[buf][off(row) + qh * 4];
            } else {
                u.q = make_uint4((quad == 2) ? ONEONE : 0u, 0u, 0u, 0u);
            }
            a1f[rt] = u.v;
        }

        // per-lane B-fragment pointer + per-jt stride (dwords)
        const unsigned int* bptr;
        int bstride;
        if (quad < 2)       { bptr = &BH[buf][off(l15) + qh * 4]; bstride = 144; }
        else if (quad == 2) { bptr = &BG[buf][l15 * 4];           bstride = 64;  }
        else                { bptr = &zero4[0];                   bstride = 0;   }

        float s00 = 0.f, s01 = 0.f, s02 = 0.f, s03 = 0.f;
        float s10 = 0.f, s11 = 0.f, s12 = 0.f, s13 = 0.f;

        // ---- pipelined main loop: MFMA tile jt, exp tile jt-1 ----
        floatx4 accP0, accP1, accC0, accC1;
        {
            FragU b; b.q = *(const uint4*)bptr; bptr += bstride;
            floatx4 zc = {0.f, 0.f, 0.f, 0.f};
            accP0 = __builtin_amdgcn_mfma_f32_16x16x32_bf16(a1f[0], b.v, zc, 0, 0, 0);
            accP1 = __builtin_amdgcn_mfma_f32_16x16x32_bf16(a1f[1], b.v, zc, 0, 0, 0);
        }
#pragma unroll
        for (int jt = 1; jt < 8; ++jt) {
            FragU b; b.q = *(const uint4*)bptr; bptr += bstride;
            floatx4 zc = {0.f, 0.f, 0.f, 0.f};
            accC0 = __builtin_amdgcn_mfma_f32_16x16x32_bf16(a1f[0], b.v, zc, 0, 0, 0);
            accC1 = __builtin_amdgcn_mfma_f32_16x16x32_bf16(a1f[1], b.v, zc, 0, 0, 0);
            s00 += __builtin_amdgcn_exp2f(accP0[0]);
            s01 += __builtin_amdgcn_exp2f(accP0[1]);
            s02 += __builtin_amdgcn_exp2f(accP0[2]);
            s03 += __builtin_amdgcn_exp2f(accP0[3]);
            s10 += __builtin_amdgcn_exp2f(accP1[0]);
            s11 += __builtin_amdgcn_exp2f(accP1[1]);
            s12 += __builtin_amdgcn_exp2f(accP1[2]);
            s13 += __builtin_amdgcn_exp2f(accP1[3]);
            accP0 = accC0;
            accP1 = accC1;
        }
        s00 += __builtin_amdgcn_exp2f(accP0[0]);
        s01 += __builtin_amdgcn_exp2f(accP0[1]);
        s02 += __builtin_amdgcn_exp2f(accP0[2]);
        s03 += __builtin_amdgcn_exp2f(accP0[3]);
        s10 += __builtin_amdgcn_exp2f(accP1[0]);
        s11 += __builtin_amdgcn_exp2f(accP1[1]);
        s12 += __builtin_amdgcn_exp2f(accP1[2]);
        s13 += __builtin_amdgcn_exp2f(accP1[3]);

        // ---- per-t epilogue: weighted row-scale into running total ----
        float wt = (t == 0 || t == 127) ? 1.f : 2.f;
        if (isxx && sq > sa) wt *= 2.f;
        const int rbase = w * 32 + quad * 4;
        const float rs00 = wt * __builtin_amdgcn_exp2f(-srg[buf][rbase + 0]);
        const float rs01 = wt * __builtin_amdgcn_exp2f(-srg[buf][rbase + 1]);
        const float rs02 = wt * __builtin_amdgcn_exp2f(-srg[buf][rbase + 2]);
        const float rs03 = wt * __builtin_amdgcn_exp2f(-srg[buf][rbase + 3]);
        const float rs10 = wt * __builtin_amdgcn_exp2f(-srg[buf][rbase + 16]);
        const float rs11 = wt * __builtin_amdgcn_exp2f(-srg[buf][rbase + 17]);
        const float rs12 = wt * __builtin_amdgcn_exp2f(-srg[buf][rbase + 18]);
        const float rs13 = wt * __builtin_amdgcn_exp2f(-srg[buf][rbase + 19]);
        tot = fmaf(s00, rs00, tot); tot = fmaf(s01, rs01, tot);
        tot = fmaf(s02, rs02, tot); tot = fmaf(s03, rs03, tot);
        tot = fmaf(s10, rs10, tot); tot = fmaf(s11, rs11, tot);
        tot = fmaf(s12, rs12, tot); tot = fmaf(s13, rs13, tot);

        // ---- stage prefetched slab into the other buffer ----
        if (tt < NT - 1) {
            __syncthreads();   // all reads of buf^1 (from tt-1) are done
            stage_row(half, r, p0, p1, p2, p3,
                      AH[buf ^ 1], BH[buf ^ 1], BG[buf ^ 1], srg[buf ^ 1]);
            __syncthreads();
        }
    }

    // ---- block reduction, one store per block ----
    for (int o = 32; o > 0; o >>= 1) tot += __shfl_down(tot, o, 64);
    if (lane == 0) red[w] = tot;
    __syncthreads();
    if (tid == 0)
        part[slot * 32 + blockIdx.y] = red[0] + red[1] + red[2] + red[3];
}

__global__ __launch_bounds__(256) void finalize_kernel(const float* __restrict__ part,
                                                       float* __restrict__ out) {
    const int tid = threadIdx.x;
    // part[slot*32+ty]: slots 0..15 xy -> idx [0,512); slots 16..25 xx -> [512,832)
    double vxy = (double)part[tid] + (double)part[256 + tid];
    double vxx = (double)part[512 + tid];
    if (tid < 64) vxx += (double)part[768 + tid];
    for (int o = 32; o > 0; o >>= 1) {
        vxx += __shfl_down(vxx, o, 64);
        vxy += __shfl_down(vxy, o, 64);
    }
    __shared__ double red[8];
    const int wid = tid >> 6;
    if ((tid & 63) == 0) { red[wid] = vxx; red[4 + wid] = vxy; }
    __syncthreads();
    if (tid == 0) {
        double sxx = red[0] + red[1] + red[2] + red[3];
        double sxy = red[4] + red[5] + red[6] + red[7];
        // diagonal entries (~1.0 each) included in sxx: subtract 254*512
        double e1 = (sxx - 254.0 * 512.0) / (254.0 * 512.0 * 511.0);
        double e2 = sxy / (254.0 * 512.0 * 512.0);
        out[0] = (float)(e1 - 2.0 * e2);
    }
}

extern "C" void kernel_launch(void* const* d_in, const int* in_sizes, int n_in,
                              void* d_out, int out_size, void* d_ws, size_t ws_size,
                              hipStream_t stream) {
    (void)in_sizes; (void)n_in; (void)out_size; (void)ws_size;
    const float* x = (const float*)d_in[0];
    const float* y = (const float*)d_in[1];
    float* out  = (float*)d_out;
    float* part = (float*)d_ws;   // 832 floats: [0,512) xy, [512,832) xx

    mmd_kernel<<<dim3(NSLOT, 32), dim3(256), 0, stream>>>(x, y, part);
    finalize_kernel<<<dim3(1), dim3(256), 0, stream>>>(part, out);
}